// Round 6
// baseline (441.571 us; speedup 1.0000x reference)
//
#include <hip/hip_runtime.h>
#include <stdint.h>

#define N_ANCH   300000
#define N_CLS    80
#define DET_DIM  85
#define TOPK     1000
#define MAXB     300
#define NMS_THR  0.4f
#define CAP      4096

// ws layout (uint32 units)
#define OFF_SBITS   0          // 300000 u32
#define OFF_TOPK    300032     // 1000 u32
#define OFF_BOXK    301056     // 1000 float4 = 4000 u32 (byte offset % 16 == 0)
#define OFF_MASK    305056     // 16000 u64 = 32000 u32  (byte offset % 8 == 0)

// ---------------- scores = max over 80 classes (pure BW pass) ----------------
__global__ __launch_bounds__(256) void k_scores(const float4* __restrict__ cls4,
                                                uint32_t* __restrict__ sbits) {
    int tid = threadIdx.x;
    int wave = tid >> 6, lane = tid & 63, g = lane >> 2, q = lane & 3;
    int row = blockIdx.x * 64 + wave * 16 + g;
    if (row >= N_ANCH) return;
    const float4* rp = cls4 + (size_t)row * 20;   // 80 floats = 20 float4
    float m = -1.0f;
    #pragma unroll
    for (int k = 0; k < 5; k++) {
        float4 v = rp[q + k * 4];
        m = fmaxf(m, fmaxf(fmaxf(v.x, v.y), fmaxf(v.z, v.w)));
    }
    m = fmaxf(m, __shfl_xor(m, 1));
    m = fmaxf(m, __shfl_xor(m, 2));
    if (q == 0) sbits[row] = __float_as_uint(m);  // scores >= 0: bit order == value order
}

// ballot-aggregated LDS histogram add: ~1 atomic per distinct bin per wave.
// Needed because level-A distribution is degenerate (~99.4% in one bin).
__device__ __forceinline__ void agg_add(uint32_t* h, uint32_t bin, bool valid) {
    int lane = threadIdx.x & 63;
    bool done = !valid;
    while (true) {
        unsigned long long rem = __ballot(!done);
        if (rem == 0ull) break;
        int leader = __ffsll((long long)rem) - 1;
        uint32_t lbin = __shfl(bin, leader);
        bool mine = (!done) && (bin == lbin);
        unsigned long long grp = __ballot(mine);
        if (lane == leader) atomicAdd(&h[lbin], (uint32_t)__popcll(grp));
        done = done || mine;
    }
}

// block-wide: find bin where the suffix (descending) count crosses K.
// WRITES TWO SLOTS: res[0]=bin, res[1]=count strictly above that bin.
// h,ps,res in LDS. 1024 thr.
__device__ __forceinline__ void findthr_block(const uint32_t* h, uint32_t* ps,
                                              uint32_t K, uint32_t* res) {
    int tid = threadIdx.x;
    uint32_t c[4]; uint32_t s = 0;
    #pragma unroll
    for (int k = 0; k < 4; k++) { c[k] = h[4095 - (tid * 4 + k)]; s += c[k]; }
    ps[tid] = s;
    __syncthreads();
    for (int off = 1; off < 1024; off <<= 1) {
        uint32_t v = (tid >= off) ? ps[tid - off] : 0;
        __syncthreads();
        ps[tid] += v;
        __syncthreads();
    }
    uint32_t incl = ps[tid], excl = incl - s;
    if (excl < K && incl >= K) {
        uint32_t run = excl;
        #pragma unroll
        for (int k = 0; k < 4; k++) {
            uint32_t nr = run + c[k];
            if (run < K && nr >= K) { res[0] = 4095 - (tid * 4 + k); res[1] = run; }
            run = nr;
        }
    }
    __syncthreads();
}

// ---------------- single-block select: histA->thrA->histB->thrB->compact->rank ----------------
// Static LDS: 16K + 4K + 32K + 24 B = ~53 KB
// mr layout: [0]=binA [1]=G_A [2]=binB [3]=G_B(scratch, clobbered by findthr) [4]=cand cnt
// R4/R5 BUG WAS HERE: cnt lived at mr[3], which findthr_block's res[1] clobbers ->
// cand[0..G_B) stayed uninitialized -> garbage idx -> global memory fault.
#define N4 (N_ANCH / 4)
#define IT4 ((N4 + 1023) / 1024)
__global__ __launch_bounds__(1024) void k_select(const uint4* __restrict__ sb4,
                                                 const float4* __restrict__ boxes4,
                                                 uint32_t* __restrict__ topk,
                                                 float4* __restrict__ boxk) {
    __shared__ uint32_t h[4096];
    __shared__ uint32_t ps[1024];
    __shared__ uint32_t mr[6];
    __shared__ unsigned long long cand[CAP];
    int tid = threadIdx.x, lane = tid & 63;

    for (int i = tid; i < 4096; i += 1024) h[i] = 0;
    if (tid == 0) mr[4] = 0;
    __syncthreads();

    // pass A: 12-bit histogram of bits[31:20]
    for (int it = 0; it < IT4; it++) {
        int t4 = it * 1024 + tid;
        bool v = t4 < N4;
        uint4 sv = v ? sb4[t4] : make_uint4(0, 0, 0, 0);
        agg_add(h, sv.x >> 20, v);
        agg_add(h, sv.y >> 20, v);
        agg_add(h, sv.z >> 20, v);
        agg_add(h, sv.w >> 20, v);
    }
    __syncthreads();
    findthr_block(h, ps, TOPK, &mr[0]);
    uint32_t binA = mr[0], GA = mr[1];
    __syncthreads();
    for (int i = tid; i < 4096; i += 1024) h[i] = 0;
    __syncthreads();

    // pass B: bits[19:8] within binA (spread across bins -> plain LDS atomics ok)
    for (int it = 0; it < IT4; it++) {
        int t4 = it * 1024 + tid;
        if (t4 < N4) {
            uint4 sv = sb4[t4];
            if ((sv.x >> 20) == binA) atomicAdd(&h[(sv.x >> 8) & 0xFFFu], 1u);
            if ((sv.y >> 20) == binA) atomicAdd(&h[(sv.y >> 8) & 0xFFFu], 1u);
            if ((sv.z >> 20) == binA) atomicAdd(&h[(sv.z >> 8) & 0xFFFu], 1u);
            if ((sv.w >> 20) == binA) atomicAdd(&h[(sv.w >> 8) & 0xFFFu], 1u);
        }
    }
    __syncthreads();
    findthr_block(h, ps, TOPK - GA, &mr[2]);   // writes mr[2] (binB) and mr[3] (scratch)
    uint32_t T24 = (binA << 12) | mr[2];

    // pass C: compact candidates (24-bit prefix >= T24) into LDS, wave-aggregated counter
    for (int it = 0; it < IT4; it++) {
        int t4 = it * 1024 + tid;
        bool v = t4 < N4;
        uint4 sv = v ? sb4[t4] : make_uint4(0, 0, 0, 0);
        uint32_t sl[4] = {sv.x, sv.y, sv.z, sv.w};
        #pragma unroll
        for (int s = 0; s < 4; s++) {
            uint32_t sb = sl[s];
            bool m = v && ((sb >> 8) >= T24);
            unsigned long long b = __ballot(m);
            if (b != 0ull) {
                int leader = __ffsll((long long)b) - 1;
                uint32_t base = 0;
                if (lane == leader) base = atomicAdd(&mr[4], (uint32_t)__popcll(b));
                base = __shfl(base, leader);
                if (m) {
                    uint32_t p = base + (uint32_t)__popcll(b & ((1ull << lane) - 1ull));
                    uint32_t idx = (uint32_t)(t4 * 4 + s);
                    if (p < CAP) cand[p] = ((unsigned long long)sb << 32) | (uint32_t)(~idx);
                }
            }
        }
    }
    __syncthreads();

    // pass D: exact rank by counting (keys unique; reproduces jax tie-break exactly).
    // inner loop index is uniform -> LDS broadcast reads, conflict-free.
    uint32_t C = mr[4]; if (C > CAP) C = CAP;
    for (int t = tid; t < (int)C; t += 1024) {
        unsigned long long my = cand[t];
        uint32_t rank = 0;
        int j = 0;
        for (; j + 4 <= (int)C; j += 4) {
            rank += (cand[j]     > my) ? 1u : 0u;
            rank += (cand[j + 1] > my) ? 1u : 0u;
            rank += (cand[j + 2] > my) ? 1u : 0u;
            rank += (cand[j + 3] > my) ? 1u : 0u;
        }
        for (; j < (int)C; j++) rank += (cand[j] > my) ? 1u : 0u;
        if (rank < TOPK) {
            uint32_t idx = ~(uint32_t)(my & 0xFFFFFFFFull);
            if (idx < N_ANCH) {            // defensive: never fault on a logic bug
                topk[rank] = idx;
                boxk[rank] = boxes4[idx];
            }
        }
    }
}

// ---------------- IoU (fp32, no fma contraction, matches reference op order) ----------------
__device__ __forceinline__ float iou_f(float4 a, float4 b) {
    #pragma clang fp contract(off)
    // box = [y1, x1, y2, x2] -> (x,y,z,w)
    float areaA = (a.z - a.x) * (a.w - a.y);
    float areaB = (b.z - b.x) * (b.w - b.y);
    float ih = fminf(a.z, b.z) - fmaxf(a.x, b.x); ih = fmaxf(ih, 0.0f);
    float iw = fminf(a.w, b.w) - fmaxf(a.y, b.y); iw = fmaxf(iw, 0.0f);
    float inter = ih * iw;
    float denom = (areaA + areaB - inter) + 1e-8f;
    return inter / denom;
}

// ---------------- suppression bitmask M[i][w] (parallel, global out) ----------------
__global__ __launch_bounds__(256) void k_mask(const float4* __restrict__ boxk,
                                              unsigned long long* __restrict__ M) {
    int tid = threadIdx.x;
    int gw = blockIdx.x * 4 + (tid >> 6);   // global wave id: 1000 rows * 16 words
    int i = gw >> 4, w = gw & 15, jl = tid & 63;
    int j = w * 64 + jl;
    float4 bi = boxk[i];
    float4 bj = boxk[j < TOPK ? j : 0];
    bool ok = (j < TOPK) && (iou_f(bi, bj) > NMS_THR);
    unsigned long long m = __ballot(ok);
    if (jl == 0) M[i * 16 + w] = m;
}

// ---------------- fused: greedy scan (wave 0) + output gather (all waves) ----------------
// Static LDS: 300*4 + 1000*4 = ~5.2 KB
__global__ __launch_bounds__(1024) void k_nmsout(const unsigned long long* __restrict__ M,
                                                 const uint32_t* __restrict__ topk,
                                                 const float* __restrict__ det,
                                                 float* __restrict__ out) {
    __shared__ int keeplS[MAXB];
    __shared__ uint32_t topkS[TOPK];
    int tid = threadIdx.x, lane = tid & 63;

    for (int i = tid; i < TOPK; i += 1024) topkS[i] = topk[i];

    if (tid < 64) {
        // ballot-reconstruction scan: row k of the 64x64 intra-chunk matrix equals
        // column k (IoU symmetry) = __ballot over lanes' own rows. kc chain is SALU.
        // Self-bit harmless: bit k of column-k ballot can't match kc (bit k not set yet).
        unsigned long long keptArr[16];
        #pragma unroll
        for (int c = 0; c < 16; c++) {
            int i = c * 64 + lane;
            unsigned long long pre = 0ull, Mic = 0ull;
            if (i < TOPK) {
                #pragma unroll
                for (int w = 0; w < c; w++) pre |= M[i * 16 + w] & keptArr[w];  // keptArr[w<c] final
                Mic = M[i * 16 + c];
            }
            unsigned long long pre_mask = __ballot(pre != 0ull);
            unsigned long long kc = 0ull;
            const int lim = (c == 15) ? (TOPK - 960) : 64;
            for (int k = 0; k < lim; k++) {
                unsigned long long b = __ballot(((Mic >> k) & 1ull) != 0ull);
                bool sup = (((pre_mask >> k) & 1ull) != 0ull) || ((b & kc) != 0ull);
                kc |= sup ? 0ull : (1ull << k);
            }
            keptArr[c] = kc;
        }
        uint32_t pfxw[16];
        uint32_t run = 0;
        #pragma unroll
        for (int w = 0; w < 16; w++) { pfxw[w] = run; run += (uint32_t)__popcll(keptArr[w]); }
        int total = (int)run; if (total > MAXB) total = MAXB;
        for (int r = total + lane; r < MAXB; r += 64) keeplS[r] = -1;  // disjoint from rank writes
        #pragma unroll
        for (int w = 0; w < 16; w++) {
            int i = w * 64 + lane;
            if (i < TOPK) {
                unsigned long long kw = keptArr[w];
                if ((kw >> lane) & 1ull) {
                    uint32_t rank = pfxw[w] + (uint32_t)__popcll(kw & ((1ull << lane) - 1ull));
                    if (rank < MAXB) keeplS[rank] = i;
                }
            }
        }
    }
    __syncthreads();

    // gather output rows (zero-fill invalid; d_out is poisoned each launch)
    for (int t = tid; t < MAXB * DET_DIM; t += 1024) {
        int r = t / DET_DIM, col = t - r * DET_DIM;
        int pos = keeplS[r];
        float v = 0.0f;
        if (pos >= 0) v = det[(size_t)topkS[pos] * DET_DIM + col];
        out[t] = v;
    }
}

extern "C" void kernel_launch(void* const* d_in, const int* in_sizes, int n_in,
                              void* d_out, int out_size, void* d_ws, size_t ws_size,
                              hipStream_t stream) {
    const float4* boxes4 = (const float4*)d_in[0];
    const float4* cls4   = (const float4*)d_in[1];
    const float*  det    = (const float*)d_in[2];
    float* out = (float*)d_out;
    uint32_t* ws = (uint32_t*)d_ws;

    uint32_t* sbits = ws + OFF_SBITS;
    uint32_t* topk  = ws + OFF_TOPK;
    float4*   boxk  = (float4*)(ws + OFF_BOXK);
    unsigned long long* M = (unsigned long long*)(ws + OFF_MASK);

    k_scores<<<(N_ANCH + 63) / 64, 256, 0, stream>>>(cls4, sbits);
    k_select<<<1, 1024, 0, stream>>>((const uint4*)sbits, boxes4, topk, boxk);
    k_mask  <<<(TOPK * 16) / 4, 256, 0, stream>>>(boxk, M);
    k_nmsout<<<1, 1024, 0, stream>>>(M, topk, det, out);
}

// Round 7
// 312.581 us; speedup vs baseline: 1.4127x; 1.4127x over previous
//
#include <hip/hip_runtime.h>
#include <stdint.h>

#define N_ANCH   300000
#define N_CLS    80
#define DET_DIM  85
#define TOPK     1000
#define MAXB     300
#define NMS_THR  0.4f
#define CAP      4096
#define NBH      32                              // blocks for hist/compact passes
#define N4       (N_ANCH / 4)
#define ITH      ((N4 + NBH*1024 - 1) / (NBH*1024))

// ws layout (uint32 units)
#define OFF_SBITS   0          // 300000 u32
#define OFF_PARTA   300032     // 32*4096 u32
#define OFF_PARTB   431104     // 32*4096 u32
#define OFF_META    562176     // 64 u32: [0]=binA [1]=G_A [4]=cand cnt
#define OFF_CAND    562240     // 4096 u64 = 8192 u32 (byte off %8==0)
#define OFF_TOPK    570432     // 1000 u32
#define OFF_BOXK    571456     // 1000 float4 (byte off %16==0)
#define OFF_MASK    575456     // 16000 u64 (byte off %8==0)

// ---------------- scores = max over 80 classes (pure BW pass) ----------------
__global__ __launch_bounds__(256) void k_scores(const float4* __restrict__ cls4,
                                                uint32_t* __restrict__ sbits,
                                                uint32_t* __restrict__ meta) {
    int tid = threadIdx.x;
    if (blockIdx.x == 0 && tid == 0) meta[4] = 0;   // candidate counter for k_compact
    int wave = tid >> 6, lane = tid & 63, g = lane >> 2, q = lane & 3;
    int row = blockIdx.x * 64 + wave * 16 + g;
    if (row >= N_ANCH) return;
    const float4* rp = cls4 + (size_t)row * 20;     // 80 floats = 20 float4
    float m = -1.0f;
    #pragma unroll
    for (int k = 0; k < 5; k++) {
        float4 v = rp[q + k * 4];
        m = fmaxf(m, fmaxf(fmaxf(v.x, v.y), fmaxf(v.z, v.w)));
    }
    m = fmaxf(m, __shfl_xor(m, 1));
    m = fmaxf(m, __shfl_xor(m, 2));
    if (q == 0) sbits[row] = __float_as_uint(m);    // scores >= 0: bit order == value order
}

// ballot-aggregated LDS histogram add: ~1 atomic per distinct bin per wave.
// Needed because level-A distribution is degenerate (~99.4% in one bin —
// plain per-lane atomics would serialize 64 same-address ops per wave).
__device__ __forceinline__ void agg_add(uint32_t* h, uint32_t bin, bool valid) {
    int lane = threadIdx.x & 63;
    bool done = !valid;
    while (true) {
        unsigned long long rem = __ballot(!done);
        if (rem == 0ull) break;
        int leader = __ffsll((long long)rem) - 1;
        uint32_t lbin = __shfl(bin, leader);
        bool mine = (!done) && (bin == lbin);
        unsigned long long grp = __ballot(mine);
        if (lane == leader) atomicAdd(&h[lbin], (uint32_t)__popcll(grp));
        done = done || mine;
    }
}

// block-wide (1024 thr): given per-thread counts c[k] for bins 4095-(tid*4+k),
// find bin where the descending-suffix count crosses K.
// Writes res[0]=bin, res[1]=count strictly above. Ends with __syncthreads().
__device__ __forceinline__ void findthr_core(const uint32_t c[4], uint32_t* ps,
                                             uint32_t K, uint32_t* res) {
    int tid = threadIdx.x;
    uint32_t s = c[0] + c[1] + c[2] + c[3];
    ps[tid] = s;
    __syncthreads();
    for (int off = 1; off < 1024; off <<= 1) {
        uint32_t v = (tid >= off) ? ps[tid - off] : 0;
        __syncthreads();
        ps[tid] += v;
        __syncthreads();
    }
    uint32_t incl = ps[tid], excl = incl - s;
    if (excl < K && incl >= K) {                   // exactly one thread matches
        uint32_t run = excl;
        #pragma unroll
        for (int k = 0; k < 4; k++) {
            uint32_t nr = run + c[k];
            if (run < K && nr >= K) { res[0] = 4095 - (tid * 4 + k); res[1] = run; }
            run = nr;
        }
    }
    __syncthreads();
}

// ---------------- level-A histogram partials (bits[31:20]), no global atomics ----------------
__global__ __launch_bounds__(1024) void k_histA(const uint4* __restrict__ sb4,
                                                uint32_t* __restrict__ part) {
    __shared__ uint32_t h[4096];
    int tid = threadIdx.x;
    for (int i = tid; i < 4096; i += 1024) h[i] = 0;
    __syncthreads();
    for (int it = 0; it < ITH; it++) {
        int t4 = (it * NBH + blockIdx.x) * 1024 + tid;
        bool v = t4 < N4;
        uint4 sv = v ? sb4[t4] : make_uint4(0, 0, 0, 0);
        agg_add(h, sv.x >> 20, v);
        agg_add(h, sv.y >> 20, v);
        agg_add(h, sv.z >> 20, v);
        agg_add(h, sv.w >> 20, v);
    }
    __syncthreads();
    for (int i = tid; i < 4096; i += 1024) part[blockIdx.x * 4096 + i] = h[i];
}

// ------- level-B partials: each block redundantly reduces A-partials + finds binA -------
__global__ __launch_bounds__(1024) void k_histB(const uint4* __restrict__ sb4,
                                                const uint32_t* __restrict__ partA,
                                                uint32_t* __restrict__ partB,
                                                uint32_t* __restrict__ meta) {
    __shared__ uint32_t h[4096];
    __shared__ uint32_t ps[1024];
    __shared__ uint32_t mr[2];
    int tid = threadIdx.x;
    uint32_t c[4];
    #pragma unroll
    for (int k = 0; k < 4; k++) {
        int bin = 4095 - (tid * 4 + k);
        uint32_t v = 0;
        #pragma unroll
        for (int r = 0; r < NBH; r++) v += partA[r * 4096 + bin];
        c[k] = v;
    }
    findthr_core(c, ps, TOPK, mr);
    uint32_t binA = mr[0];
    if (blockIdx.x == 0 && tid == 0) { meta[0] = mr[0]; meta[1] = mr[1]; }
    for (int i = tid; i < 4096; i += 1024) h[i] = 0;
    __syncthreads();
    // conditioned hist on bits[19:8]: values spread over 4096 bins -> plain LDS atomics ok
    for (int it = 0; it < ITH; it++) {
        int t4 = (it * NBH + blockIdx.x) * 1024 + tid;
        if (t4 < N4) {
            uint4 sv = sb4[t4];
            if ((sv.x >> 20) == binA) atomicAdd(&h[(sv.x >> 8) & 0xFFFu], 1u);
            if ((sv.y >> 20) == binA) atomicAdd(&h[(sv.y >> 8) & 0xFFFu], 1u);
            if ((sv.z >> 20) == binA) atomicAdd(&h[(sv.z >> 8) & 0xFFFu], 1u);
            if ((sv.w >> 20) == binA) atomicAdd(&h[(sv.w >> 8) & 0xFFFu], 1u);
        }
    }
    __syncthreads();
    for (int i = tid; i < 4096; i += 1024) partB[blockIdx.x * 4096 + i] = h[i];
}

// ------- compact: redundant reduce of B-partials + findthr, then 2-phase, 1 atomic/block -------
__global__ __launch_bounds__(1024) void k_compact(const uint4* __restrict__ sb4,
                                                  const uint32_t* __restrict__ partB,
                                                  const uint32_t* __restrict__ meta,
                                                  uint32_t* __restrict__ cnt,
                                                  unsigned long long* __restrict__ cand) {
    __shared__ uint32_t ps[1024];
    __shared__ uint32_t mr[2];
    __shared__ uint32_t wsum[16];
    int tid = threadIdx.x, wave = tid >> 6, lane = tid & 63;
    uint32_t binA = meta[0], GA = meta[1];
    uint32_t c[4];
    #pragma unroll
    for (int k = 0; k < 4; k++) {
        int bin = 4095 - (tid * 4 + k);
        uint32_t v = 0;
        #pragma unroll
        for (int r = 0; r < NBH; r++) v += partB[r * 4096 + bin];
        c[k] = v;
    }
    findthr_core(c, ps, TOPK - GA, mr);
    uint32_t T24 = (binA << 12) | mr[0];
    // phase 1: per-wave candidate counts
    uint32_t cw = 0;
    for (int it = 0; it < ITH; it++) {
        int t4 = (it * NBH + blockIdx.x) * 1024 + tid;
        bool v = t4 < N4;
        uint4 sv = v ? sb4[t4] : make_uint4(0, 0, 0, 0);
        uint32_t sl[4] = {sv.x, sv.y, sv.z, sv.w};
        #pragma unroll
        for (int s = 0; s < 4; s++) {
            bool m = v && ((sl[s] >> 8) >= T24);
            cw += (uint32_t)__popcll(__ballot(m));
        }
    }
    if (lane == 0) wsum[wave] = cw;
    __syncthreads();
    if (tid == 0) {
        uint32_t tot = 0;
        #pragma unroll
        for (int w = 0; w < 16; w++) tot += wsum[w];
        uint32_t base = atomicAdd(cnt, tot);       // the ONE global atomic per block
        uint32_t r = base;
        #pragma unroll
        for (int w = 0; w < 16; w++) { uint32_t c0 = wsum[w]; wsum[w] = r; r += c0; }
    }
    __syncthreads();
    uint32_t wbase = wsum[wave];
    // phase 2: identical iteration order -> rank-stable slots (cand order is irrelevant anyway)
    for (int it = 0; it < ITH; it++) {
        int t4 = (it * NBH + blockIdx.x) * 1024 + tid;
        bool v = t4 < N4;
        uint4 sv = v ? sb4[t4] : make_uint4(0, 0, 0, 0);
        uint32_t sl[4] = {sv.x, sv.y, sv.z, sv.w};
        #pragma unroll
        for (int s = 0; s < 4; s++) {
            uint32_t sb = sl[s];
            bool m = v && ((sb >> 8) >= T24);
            unsigned long long b = __ballot(m);
            if (m) {
                uint32_t p = wbase + (uint32_t)__popcll(b & ((1ull << lane) - 1ull));
                uint32_t idx = (uint32_t)(t4 * 4 + s);
                if (p < CAP) cand[p] = ((unsigned long long)sb << 32) | (uint32_t)(~idx);
            }
            wbase += (uint32_t)__popcll(b);
        }
    }
}

// ---------------- exact rank by counting ----------------
// keys unique ((sb<<32)|~idx); all top-1000 are in cand (C >= 1000 by construction);
// rank = #{j: key_j > key_i} reproduces jax's (value desc, index asc) order exactly.
__global__ __launch_bounds__(1024) void k_rank(const unsigned long long* __restrict__ cand,
                                               const uint32_t* __restrict__ cnt,
                                               uint32_t* __restrict__ topk,
                                               const float4* __restrict__ boxes4,
                                               float4* __restrict__ boxk) {
    int t = blockIdx.x * 1024 + threadIdx.x;
    uint32_t C = *cnt; if (C > CAP) C = CAP;
    if (t >= (int)C) return;
    unsigned long long my = cand[t];
    uint32_t rank = 0;
    int j = 0;
    for (; j + 4 <= (int)C; j += 4) {              // uniform j -> wave-broadcast L2 loads
        rank += (cand[j]     > my) ? 1u : 0u;
        rank += (cand[j + 1] > my) ? 1u : 0u;
        rank += (cand[j + 2] > my) ? 1u : 0u;
        rank += (cand[j + 3] > my) ? 1u : 0u;
    }
    for (; j < (int)C; j++) rank += (cand[j] > my) ? 1u : 0u;
    if (rank < TOPK) {
        uint32_t idx = ~(uint32_t)(my & 0xFFFFFFFFull);
        if (idx < N_ANCH) {                        // defensive: never fault on a logic bug
            topk[rank] = idx;
            boxk[rank] = boxes4[idx];
        }
    }
}

// ---------------- IoU (fp32, no fma contraction, matches reference op order) ----------------
__device__ __forceinline__ float iou_f(float4 a, float4 b) {
    #pragma clang fp contract(off)
    // box = [y1, x1, y2, x2] -> (x,y,z,w)
    float areaA = (a.z - a.x) * (a.w - a.y);
    float areaB = (b.z - b.x) * (b.w - b.y);
    float ih = fminf(a.z, b.z) - fmaxf(a.x, b.x); ih = fmaxf(ih, 0.0f);
    float iw = fminf(a.w, b.w) - fmaxf(a.y, b.y); iw = fmaxf(iw, 0.0f);
    float inter = ih * iw;
    float denom = (areaA + areaB - inter) + 1e-8f;
    return inter / denom;
}

// ---------------- suppression bitmask M[i][w] (parallel, global out) ----------------
__global__ __launch_bounds__(256) void k_mask(const float4* __restrict__ boxk,
                                              unsigned long long* __restrict__ M) {
    int tid = threadIdx.x;
    int gw = blockIdx.x * 4 + (tid >> 6);   // global wave id: 1000 rows * 16 words
    int i = gw >> 4, w = gw & 15, jl = tid & 63;
    int j = w * 64 + jl;
    float4 bi = boxk[i];
    float4 bj = boxk[j < TOPK ? j : 0];
    bool ok = (j < TOPK) && (iou_f(bi, bj) > NMS_THR);
    unsigned long long m = __ballot(ok);
    if (jl == 0) M[i * 16 + w] = m;
}

// ---------------- fused: greedy scan (wave 0) + output gather (all waves) ----------------
__global__ __launch_bounds__(1024) void k_nmsout(const unsigned long long* __restrict__ M,
                                                 const uint32_t* __restrict__ topk,
                                                 const float* __restrict__ det,
                                                 float* __restrict__ out) {
    __shared__ int keeplS[MAXB];
    __shared__ uint32_t topkS[TOPK];
    int tid = threadIdx.x, lane = tid & 63;

    for (int i = tid; i < TOPK; i += 1024) topkS[i] = topk[i];

    if (tid < 64) {
        // ballot-reconstruction scan: row k of the 64x64 intra-chunk matrix equals
        // column k (IoU symmetry) = __ballot over lanes' own rows. kc chain is SALU.
        // Self-bit harmless: bit k of column-k ballot can't match kc (bit k not set yet).
        unsigned long long keptArr[16];
        #pragma unroll
        for (int c = 0; c < 16; c++) {
            int i = c * 64 + lane;
            unsigned long long pre = 0ull, Mic = 0ull;
            if (i < TOPK) {
                #pragma unroll
                for (int w = 0; w < c; w++) pre |= M[i * 16 + w] & keptArr[w];  // keptArr[w<c] final
                Mic = M[i * 16 + c];
            }
            unsigned long long pre_mask = __ballot(pre != 0ull);
            unsigned long long kc = 0ull;
            const int lim = (c == 15) ? (TOPK - 960) : 64;
            for (int k = 0; k < lim; k++) {
                unsigned long long b = __ballot(((Mic >> k) & 1ull) != 0ull);
                bool sup = (((pre_mask >> k) & 1ull) != 0ull) || ((b & kc) != 0ull);
                kc |= sup ? 0ull : (1ull << k);
            }
            keptArr[c] = kc;
        }
        uint32_t pfxw[16];
        uint32_t run = 0;
        #pragma unroll
        for (int w = 0; w < 16; w++) { pfxw[w] = run; run += (uint32_t)__popcll(keptArr[w]); }
        int total = (int)run; if (total > MAXB) total = MAXB;
        for (int r = total + lane; r < MAXB; r += 64) keeplS[r] = -1;  // disjoint from rank writes
        #pragma unroll
        for (int w = 0; w < 16; w++) {
            int i = w * 64 + lane;
            if (i < TOPK) {
                unsigned long long kw = keptArr[w];
                if ((kw >> lane) & 1ull) {
                    uint32_t rank = pfxw[w] + (uint32_t)__popcll(kw & ((1ull << lane) - 1ull));
                    if (rank < MAXB) keeplS[rank] = i;
                }
            }
        }
    }
    __syncthreads();

    // gather output rows (zero-fill invalid; d_out is poisoned each launch)
    for (int t = tid; t < MAXB * DET_DIM; t += 1024) {
        int r = t / DET_DIM, col = t - r * DET_DIM;
        int pos = keeplS[r];
        float v = 0.0f;
        if (pos >= 0) v = det[(size_t)topkS[pos] * DET_DIM + col];
        out[t] = v;
    }
}

extern "C" void kernel_launch(void* const* d_in, const int* in_sizes, int n_in,
                              void* d_out, int out_size, void* d_ws, size_t ws_size,
                              hipStream_t stream) {
    const float4* boxes4 = (const float4*)d_in[0];
    const float4* cls4   = (const float4*)d_in[1];
    const float*  det    = (const float*)d_in[2];
    float* out = (float*)d_out;
    uint32_t* ws = (uint32_t*)d_ws;

    uint32_t* sbits = ws + OFF_SBITS;
    uint32_t* partA = ws + OFF_PARTA;
    uint32_t* partB = ws + OFF_PARTB;
    uint32_t* meta  = ws + OFF_META;
    unsigned long long* cand = (unsigned long long*)(ws + OFF_CAND);
    uint32_t* topk  = ws + OFF_TOPK;
    float4*   boxk  = (float4*)(ws + OFF_BOXK);
    unsigned long long* M = (unsigned long long*)(ws + OFF_MASK);

    k_scores <<<(N_ANCH + 63) / 64, 256, 0, stream>>>(cls4, sbits, meta);
    k_histA  <<<NBH, 1024, 0, stream>>>((const uint4*)sbits, partA);
    k_histB  <<<NBH, 1024, 0, stream>>>((const uint4*)sbits, partA, partB, meta);
    k_compact<<<NBH, 1024, 0, stream>>>((const uint4*)sbits, partB, meta, &meta[4], cand);
    k_rank   <<<CAP / 1024, 1024, 0, stream>>>(cand, &meta[4], topk, boxes4, boxk);
    k_mask   <<<(TOPK * 16) / 4, 256, 0, stream>>>(boxk, M);
    k_nmsout <<<1, 1024, 0, stream>>>(M, topk, det, out);
}